// Round 1
// baseline (628.117 us; speedup 1.0000x reference)
//
#include <hip/hip_runtime.h>
#include <stdint.h>

#define NB 8
#define NT 1024
#define ND 768
#define NV 768
#define NL 13
#define NQK 32
#define NH 4
#define NHD 8
#define MTOK (NB*NT)          // 8192
#define MROWS (MTOK*NL)       // 106496

typedef __attribute__((ext_vector_type(8))) short short8;
typedef __attribute__((ext_vector_type(4))) float f32x4;

__device__ __forceinline__ unsigned short f2bf(float f) {
    union { float f; unsigned u; } v; v.f = f;
    unsigned r = v.u + 0x7FFFu + ((v.u >> 16) & 1u);
    return (unsigned short)(r >> 16);
}
__device__ __forceinline__ float bf2f(unsigned short u) {
    union { unsigned u; float f; } v; v.u = ((unsigned)u) << 16;
    return v.f;
}

// ---------------------------------------------------------------------------
// Generic 128x128 MFMA GEMM, C = A * B^T + bias.  A: [M][K] (f32 or bf16),
// B: [N][K] f32 (K-contiguous, i.e. "NT" form), bias: [N].
// grid = (N/128, M/128, L)
// ---------------------------------------------------------------------------
template<bool ABF16, bool CF32>
__global__ __launch_bounds__(256) void mfma_gemm_bias(
    const void* __restrict__ Abase, const float* __restrict__ Bbase,
    const float* __restrict__ biasBase, void* __restrict__ Cbase,
    int K, long aLayerStride, long bLayerStride, int biasLayerStride,
    long cLayerOff, long cRowStride)
{
    __shared__ __align__(16) unsigned short lsA[128 * 40];
    __shared__ __align__(16) unsigned short lsB[128 * 40];

    const int l  = blockIdx.z;
    const int m0 = blockIdx.y * 128;
    const int n0 = blockIdx.x * 128;
    const int t  = threadIdx.x;

    const float* Bw   = Bbase + (size_t)l * bLayerStride;
    const float* bias = biasBase + (size_t)l * biasLayerStride;

    const int lane = t & 63;
    const int wave = t >> 6;
    const int wm = (wave >> 1) * 64;
    const int wn = (wave & 1) * 64;
    const int lr = lane & 15;
    const int kg = (lane >> 4) * 8;

    f32x4 acc[4][4];
#pragma unroll
    for (int i = 0; i < 4; i++)
#pragma unroll
        for (int j = 0; j < 4; j++) acc[i][j] = (f32x4){0.f, 0.f, 0.f, 0.f};

    const int row_s = t >> 3;   // 0..31
    const int c4    = t & 7;    // 0..7 (float4 column)

    for (int k0 = 0; k0 < K; k0 += 32) {
#pragma unroll
        for (int i = 0; i < 4; i++) {
            int row = row_s + 32 * i;
            // A tile
            ushort4 va;
            size_t aoff = (size_t)l * aLayerStride + (size_t)(m0 + row) * K + (k0 + c4 * 4);
            if constexpr (ABF16) {
                va = *(const ushort4*)((const unsigned short*)Abase + aoff);
            } else {
                float4 f = *(const float4*)((const float*)Abase + aoff);
                va.x = f2bf(f.x); va.y = f2bf(f.y); va.z = f2bf(f.z); va.w = f2bf(f.w);
            }
            *(ushort4*)&lsA[row * 40 + c4 * 4] = va;
            // B tile
            float4 fb = *(const float4*)(Bw + (size_t)(n0 + row) * K + (k0 + c4 * 4));
            ushort4 vb;
            vb.x = f2bf(fb.x); vb.y = f2bf(fb.y); vb.z = f2bf(fb.z); vb.w = f2bf(fb.w);
            *(ushort4*)&lsB[row * 40 + c4 * 4] = vb;
        }
        __syncthreads();

        short8 af[4], bfv[4];
#pragma unroll
        for (int mi = 0; mi < 4; mi++)
            af[mi] = *(const short8*)&lsA[(wm + mi * 16 + lr) * 40 + kg];
#pragma unroll
        for (int ni = 0; ni < 4; ni++)
            bfv[ni] = *(const short8*)&lsB[(wn + ni * 16 + lr) * 40 + kg];
#pragma unroll
        for (int mi = 0; mi < 4; mi++)
#pragma unroll
            for (int ni = 0; ni < 4; ni++)
                acc[mi][ni] = __builtin_amdgcn_mfma_f32_16x16x32_bf16(
                    af[mi], bfv[ni], acc[mi][ni], 0, 0, 0);
        __syncthreads();
    }

#pragma unroll
    for (int ni = 0; ni < 4; ni++) {
        int col = n0 + wn + ni * 16 + lr;
        float bv = bias[col];
#pragma unroll
        for (int mi = 0; mi < 4; mi++) {
#pragma unroll
            for (int r = 0; r < 4; r++) {
                int grow = m0 + wm + mi * 16 + (lane >> 4) * 4 + r;
                float val = acc[mi][ni][r] + bv;
                size_t coff = (size_t)grow * cRowStride + (size_t)l * cLayerOff + col;
                if constexpr (CF32) ((float*)Cbase)[coff] = val;
                else                ((unsigned short*)Cbase)[coff] = f2bf(val);
            }
        }
    }
}

// ---------------------------------------------------------------------------
// LayerNorm over rows of length 768.  One wave per row, 4 rows per block.
// ---------------------------------------------------------------------------
template<bool SRCF32>
__global__ __launch_bounds__(256) void ln_rows(
    const void* __restrict__ src, unsigned short* __restrict__ dst,
    const float* __restrict__ gam, const float* __restrict__ bet)
{
    const int lane = threadIdx.x & 63;
    const int wave = threadIdx.x >> 6;
    const size_t row = (size_t)blockIdx.x * 4 + wave;

    float x[3][4];
    float s = 0.f, sq = 0.f;
#pragma unroll
    for (int i = 0; i < 3; i++) {
        int v = i * 256 + lane * 4;
        if constexpr (SRCF32) {
            float4 f = *(const float4*)((const float*)src + row * 768 + v);
            x[i][0] = f.x; x[i][1] = f.y; x[i][2] = f.z; x[i][3] = f.w;
        } else {
            ushort4 u = *(const ushort4*)((const unsigned short*)src + row * 768 + v);
            x[i][0] = bf2f(u.x); x[i][1] = bf2f(u.y); x[i][2] = bf2f(u.z); x[i][3] = bf2f(u.w);
        }
#pragma unroll
        for (int e = 0; e < 4; e++) { s += x[i][e]; sq += x[i][e] * x[i][e]; }
    }
#pragma unroll
    for (int off = 1; off < 64; off <<= 1) {
        s  += __shfl_xor(s, off);
        sq += __shfl_xor(sq, off);
    }
    float mean = s * (1.f / 768.f);
    float var  = sq * (1.f / 768.f) - mean * mean;
    float rs   = rsqrtf(var + 1e-5f);
#pragma unroll
    for (int i = 0; i < 3; i++) {
        int v = i * 256 + lane * 4;
        float4 g = *(const float4*)(gam + v);
        float4 b = *(const float4*)(bet + v);
        ushort4 o;
        o.x = f2bf((x[i][0] - mean) * rs * g.x + b.x);
        o.y = f2bf((x[i][1] - mean) * rs * g.y + b.y);
        o.z = f2bf((x[i][2] - mean) * rs * g.z + b.z);
        o.w = f2bf((x[i][3] - mean) * rs * g.w + b.w);
        *(ushort4*)(dst + row * 768 + v) = o;
    }
}

// ---------------------------------------------------------------------------
// out[M][32] = A[M][768](bf16) @ W[32][768]^T + bias.  W resident in LDS.
// grid = M/128, 256 threads (4 waves x 32 rows).
// ---------------------------------------------------------------------------
__global__ __launch_bounds__(256) void proj32(
    const unsigned short* __restrict__ A, const float* __restrict__ W,
    const float* __restrict__ bias, unsigned short* __restrict__ out)
{
    __shared__ __align__(16) unsigned short lsW[32 * 776];
    __shared__ __align__(16) unsigned short lsA[128 * 40];
    const int t = threadIdx.x;

#pragma unroll
    for (int i = 0; i < 24; i++) {
        int fi = t + i * 256;
        int row = fi / 192;
        int c4  = fi % 192;
        float4 f = *(const float4*)(W + row * 768 + c4 * 4);
        ushort4 u;
        u.x = f2bf(f.x); u.y = f2bf(f.y); u.z = f2bf(f.z); u.w = f2bf(f.w);
        *(ushort4*)&lsW[row * 776 + c4 * 4] = u;
    }

    const size_t m0 = (size_t)blockIdx.x * 128;
    const int lane = t & 63, wave = t >> 6;
    const int wm = wave * 32;
    const int lr = lane & 15, kg = (lane >> 4) * 8;
    const int row_s = t >> 3, c4s = t & 7;

    f32x4 acc[2][2];
#pragma unroll
    for (int i = 0; i < 2; i++)
#pragma unroll
        for (int j = 0; j < 2; j++) acc[i][j] = (f32x4){0.f, 0.f, 0.f, 0.f};

    __syncthreads();

    for (int k0 = 0; k0 < 768; k0 += 32) {
#pragma unroll
        for (int i = 0; i < 4; i++) {
            int row = row_s + 32 * i;
            ushort4 v = *(const ushort4*)(A + (m0 + row) * 768 + k0 + c4s * 4);
            *(ushort4*)&lsA[row * 40 + c4s * 4] = v;
        }
        __syncthreads();
        short8 af[2], bw[2];
#pragma unroll
        for (int mi = 0; mi < 2; mi++)
            af[mi] = *(const short8*)&lsA[(wm + mi * 16 + lr) * 40 + kg];
#pragma unroll
        for (int ni = 0; ni < 2; ni++)
            bw[ni] = *(const short8*)&lsW[(ni * 16 + lr) * 776 + k0 + kg];
#pragma unroll
        for (int mi = 0; mi < 2; mi++)
#pragma unroll
            for (int ni = 0; ni < 2; ni++)
                acc[mi][ni] = __builtin_amdgcn_mfma_f32_16x16x32_bf16(
                    af[mi], bw[ni], acc[mi][ni], 0, 0, 0);
        __syncthreads();
    }

#pragma unroll
    for (int ni = 0; ni < 2; ni++) {
        int col = ni * 16 + lr;
        float bv = bias[col];
#pragma unroll
        for (int mi = 0; mi < 2; mi++) {
#pragma unroll
            for (int r = 0; r < 4; r++) {
                size_t grow = m0 + wm + mi * 16 + (lane >> 4) * 4 + r;
                out[grow * 32 + col] = f2bf(acc[mi][ni][r] + bv);
            }
        }
    }
}

// ---------------------------------------------------------------------------
// Attention: scores -> softmax(L=13) -> out_heads.  One wave per token.
// ---------------------------------------------------------------------------
__global__ __launch_bounds__(256) void attn_kernel(
    const unsigned short* __restrict__ qb, const unsigned short* __restrict__ kb,
    const unsigned short* __restrict__ kv, unsigned short* __restrict__ oh)
{
    __shared__ float lat[4][4][13];
    const int t = threadIdx.x, lane = t & 63, wave = t >> 6;
    const size_t m = (size_t)blockIdx.x * 4 + wave;

    if (lane < 32) {
        int j = lane;
        float qv = bf2f(qb[m * 32 + j]);
        float p[13];
#pragma unroll
        for (int l = 0; l < 13; l++)
            p[l] = qv * bf2f(kb[(m * 13 + l) * 32 + j]);
#pragma unroll
        for (int off = 1; off < 8; off <<= 1)
#pragma unroll
            for (int l = 0; l < 13; l++) p[l] += __shfl_xor(p[l], off);

        const float sc = 0.17677669529663687f; // 1 / (sqrt(8) * 2)
        float mx = -1e30f;
#pragma unroll
        for (int l = 0; l < 13; l++) { p[l] *= sc; mx = fmaxf(mx, p[l]); }
        float se = 0.f;
#pragma unroll
        for (int l = 0; l < 13; l++) { p[l] = __expf(p[l] - mx); se += p[l]; }
        float inv = 1.f / se;
        if ((j & 7) == 0) {
#pragma unroll
            for (int l = 0; l < 13; l++) lat[wave][j >> 3][l] = p[l] * inv;
        }
    }
    __syncthreads();

    float acc[4][3][4];
#pragma unroll
    for (int h = 0; h < 4; h++)
#pragma unroll
        for (int i = 0; i < 3; i++)
#pragma unroll
            for (int e = 0; e < 4; e++) acc[h][i][e] = 0.f;

    for (int l = 0; l < 13; l++) {
        float al[4];
#pragma unroll
        for (int h = 0; h < 4; h++) al[h] = lat[wave][h][l];
#pragma unroll
        for (int i = 0; i < 3; i++) {
            ushort4 u = *(const ushort4*)(kv + (m * 13 + l) * 768 + i * 256 + lane * 4);
            float xv[4] = {bf2f(u.x), bf2f(u.y), bf2f(u.z), bf2f(u.w)};
#pragma unroll
            for (int h = 0; h < 4; h++)
#pragma unroll
                for (int e = 0; e < 4; e++) acc[h][i][e] += al[h] * xv[e];
        }
    }
#pragma unroll
    for (int h = 0; h < 4; h++)
#pragma unroll
        for (int i = 0; i < 3; i++) {
            ushort4 o;
            o.x = f2bf(acc[h][i][0]); o.y = f2bf(acc[h][i][1]);
            o.z = f2bf(acc[h][i][2]); o.w = f2bf(acc[h][i][3]);
            *(ushort4*)(oh + m * 3072 + h * 768 + i * 256 + lane * 4) = o;
        }
}

// ---------------------------------------------------------------------------
extern "C" void kernel_launch(void* const* d_in, const int* in_sizes, int n_in,
                              void* d_out, int out_size, void* d_ws, size_t ws_size,
                              hipStream_t stream) {
    const float* base  = (const float*)d_in[0];   // (B,T,D)
    const float* reps  = (const float*)d_in[1];   // (L,B,T,R)
    const float* aw    = (const float*)d_in[2];   // (L,V,R)
    const float* ab    = (const float*)d_in[3];   // (L,V)
    const float* qg    = (const float*)d_in[4];
    const float* qbeta = (const float*)d_in[5];
    const float* kvg   = (const float*)d_in[6];
    const float* kvb   = (const float*)d_in[7];
    const float* qw    = (const float*)d_in[8];   // (32,768)
    const float* qbias = (const float*)d_in[9];
    const float* kw    = (const float*)d_in[10];  // (32,768)
    const float* kbias = (const float*)d_in[11];
    const float* ow    = (const float*)d_in[12];  // (768,3072)
    const float* obias = (const float*)d_in[13];
    float* out = (float*)d_out;

    unsigned short* aligned = (unsigned short*)d_ws;                 // [MROWS][768] bf16
    unsigned short* Qn   = aligned + (size_t)MROWS * 768;            // [8192][768]
    unsigned short* kbuf = Qn + (size_t)MTOK * 768;                  // [MROWS][32]
    unsigned short* qbuf = kbuf + (size_t)MROWS * 32;                // [8192][32]
    unsigned short* oh   = qbuf + (size_t)MTOK * 32;                 // [8192][3072]

    // 1. aligned = layer_reps @ aligner_w^T + aligner_b  (13 layers), bf16
    dim3 g1(NV / 128, MTOK / 128, NL);
    mfma_gemm_bias<false, false><<<g1, 256, 0, stream>>>(
        reps, aw, ab, aligned,
        768, (long)MTOK * 768, (long)768 * 768, 768, 768L, (long)NL * 768);

    // 2. LayerNorms
    ln_rows<false><<<MROWS / 4, 256, 0, stream>>>(aligned, aligned, kvg, kvb);
    ln_rows<true><<<MTOK / 4, 256, 0, stream>>>(base, Qn, qg, qbeta);

    // 3. k/q projections
    proj32<<<MROWS / 128, 256, 0, stream>>>(aligned, kw, kbias, kbuf);
    proj32<<<MTOK / 128, 256, 0, stream>>>(Qn, qw, qbias, qbuf);

    // 4. attention -> out_heads
    attn_kernel<<<MTOK / 4, 256, 0, stream>>>(qbuf, kbuf, aligned, oh);

    // 5. out = out_heads @ out_w^T + out_b  (fp32 out)
    dim3 g2(ND / 128, MTOK / 128, 1);
    mfma_gemm_bias<true, true><<<g2, 256, 0, stream>>>(
        oh, ow, obias, out,
        3072, 0L, 0L, 0, 0L, 768L);
}

// Round 2
// 577.746 us; speedup vs baseline: 1.0872x; 1.0872x over previous
//
#include <hip/hip_runtime.h>
#include <stdint.h>

#define NB 8
#define NT 1024
#define ND 768
#define NV 768
#define NL 13
#define MTOK (NB*NT)          // 8192
#define MROWS (MTOK*NL)       // 106496

typedef __attribute__((ext_vector_type(8))) short short8;
typedef __attribute__((ext_vector_type(4))) float f32x4;

__device__ __forceinline__ unsigned short f2bf(float f) {
    union { float f; unsigned u; } v; v.f = f;
    unsigned r = v.u + 0x7FFFu + ((v.u >> 16) & 1u);
    return (unsigned short)(r >> 16);
}
__device__ __forceinline__ float bf2f(unsigned short u) {
    union { unsigned u; float f; } v; v.u = ((unsigned)u) << 16;
    return v.f;
}

__device__ __forceinline__ void gload16(const void* g, void* l) {
    __builtin_amdgcn_global_load_lds(
        (const __attribute__((address_space(1))) unsigned int*)g,
        (__attribute__((address_space(3))) unsigned int*)l, 16, 0, 0);
}

// ---------------------------------------------------------------------------
// fp32 -> bf16 bulk convert
// ---------------------------------------------------------------------------
__global__ __launch_bounds__(256) void conv_f32_bf16(
    const float* __restrict__ s, unsigned short* __restrict__ d, long n)
{
    long i = ((long)blockIdx.x * 256 + threadIdx.x) * 8;
    long st = (long)gridDim.x * 2048;
    for (; i < n; i += st) {
        float4 a = *(const float4*)(s + i);
        float4 b = *(const float4*)(s + i + 4);
        ushort4 u0, u1;
        u0.x = f2bf(a.x); u0.y = f2bf(a.y); u0.z = f2bf(a.z); u0.w = f2bf(a.w);
        u1.x = f2bf(b.x); u1.y = f2bf(b.y); u1.z = f2bf(b.z); u1.w = f2bf(b.w);
        *(ushort4*)(d + i)     = u0;
        *(ushort4*)(d + i + 4) = u1;
    }
}

// ---------------------------------------------------------------------------
// m97-structure bf16 GEMM: C = A * B^T + bias.
// A: [L][M][K] bf16, B: [L][N][K] bf16 (both K-contiguous), bias fp32 [L][N].
// 128x128 tile, BK=32, double-buffered LDS, global_load_lds width=16.
// grid = (N/128, M/128, L), 256 threads.
// ---------------------------------------------------------------------------
template<bool CF32>
__global__ __launch_bounds__(256) void gemm_bf16_nt(
    const unsigned short* __restrict__ A, const unsigned short* __restrict__ B,
    const float* __restrict__ biasBase, void* __restrict__ Cbase,
    int K, long aLS, long bLS, int biasLS, long cLayerOff, long cRowStride)
{
    __shared__ __align__(16) unsigned short lsA[2][128 * 32];
    __shared__ __align__(16) unsigned short lsB[2][128 * 32];

    const int l = blockIdx.z;
    const long m0 = (long)blockIdx.y * 128;
    const long n0 = (long)blockIdx.x * 128;
    const int t = threadIdx.x, lane = t & 63, wave = t >> 6;

    const unsigned short* Ab = A + (size_t)l * aLS;
    const unsigned short* Bb = B + (size_t)l * bLS;
    const float* bias = biasBase + (size_t)l * biasLS;

    // staging: dest byte d covers linear [128][32] bf16 tile (64B per row)
    const int d0 = wave * 1024 + lane * 16;   // issue 0: rows 0..63
    const int r0 = d0 >> 6, cb = d0 & 63;
    const int r1 = r0 + 64;                   // issue 1: rows 64..127
    const char* aS0 = (const char*)(Ab + (m0 + r0) * (size_t)K) + cb;
    const char* aS1 = (const char*)(Ab + (m0 + r1) * (size_t)K) + cb;
    const char* bS0 = (const char*)(Bb + (n0 + r0) * (size_t)K) + cb;
    const char* bS1 = (const char*)(Bb + (n0 + r1) * (size_t)K) + cb;

    const int wm = (wave >> 1) * 64;
    const int wn = (wave & 1) * 64;
    const int lr = lane & 15;
    const int kg = (lane >> 4) * 8;

    f32x4 acc[4][4];
#pragma unroll
    for (int i = 0; i < 4; i++)
#pragma unroll
        for (int j = 0; j < 4; j++) acc[i][j] = (f32x4){0.f, 0.f, 0.f, 0.f};

    auto STAGE = [&](int buf, int k0) {
        long kb = (long)k0 * 2;
        char* la = (char*)lsA[buf];
        char* lb = (char*)lsB[buf];
        gload16(aS0 + kb, la + d0);
        gload16(aS1 + kb, la + d0 + 4096);
        gload16(bS0 + kb, lb + d0);
        gload16(bS1 + kb, lb + d0 + 4096);
    };
    auto COMP = [&](int buf) {
        short8 af[4], bv[4];
        const unsigned short* pa = lsA[buf];
        const unsigned short* pb = lsB[buf];
#pragma unroll
        for (int mi = 0; mi < 4; mi++)
            af[mi] = *(const short8*)&pa[(wm + mi * 16 + lr) * 32 + kg];
#pragma unroll
        for (int ni = 0; ni < 4; ni++)
            bv[ni] = *(const short8*)&pb[(wn + ni * 16 + lr) * 32 + kg];
#pragma unroll
        for (int mi = 0; mi < 4; mi++)
#pragma unroll
            for (int ni = 0; ni < 4; ni++)
                acc[mi][ni] = __builtin_amdgcn_mfma_f32_16x16x32_bf16(
                    af[mi], bv[ni], acc[mi][ni], 0, 0, 0);
    };

    STAGE(0, 0);
    __syncthreads();
    int cur = 0;
    const int nst = K >> 5;
    for (int ks = 1; ks < nst; ks++) {
        STAGE(cur ^ 1, ks * 32);
        COMP(cur);
        __syncthreads();
        cur ^= 1;
    }
    COMP(cur);

#pragma unroll
    for (int ni = 0; ni < 4; ni++) {
        long col = n0 + wn + ni * 16 + lr;
        float bv = bias[col];
#pragma unroll
        for (int mi = 0; mi < 4; mi++) {
#pragma unroll
            for (int r = 0; r < 4; r++) {
                long grow = m0 + wm + mi * 16 + (lane >> 4) * 4 + r;
                float val = acc[mi][ni][r] + bv;
                size_t coff = (size_t)grow * cRowStride + (size_t)l * cLayerOff + col;
                if constexpr (CF32) ((float*)Cbase)[coff] = val;
                else                ((unsigned short*)Cbase)[coff] = f2bf(val);
            }
        }
    }
}

// ---------------------------------------------------------------------------
// LayerNorm over rows of length 768.  One wave per row, 4 rows per block.
// ---------------------------------------------------------------------------
template<bool SRCF32>
__global__ __launch_bounds__(256) void ln_rows(
    const void* __restrict__ src, unsigned short* __restrict__ dst,
    const float* __restrict__ gam, const float* __restrict__ bet)
{
    const int lane = threadIdx.x & 63;
    const int wave = threadIdx.x >> 6;
    const size_t row = (size_t)blockIdx.x * 4 + wave;

    float x[3][4];
    float s = 0.f, sq = 0.f;
#pragma unroll
    for (int i = 0; i < 3; i++) {
        int v = i * 256 + lane * 4;
        if constexpr (SRCF32) {
            float4 f = *(const float4*)((const float*)src + row * 768 + v);
            x[i][0] = f.x; x[i][1] = f.y; x[i][2] = f.z; x[i][3] = f.w;
        } else {
            ushort4 u = *(const ushort4*)((const unsigned short*)src + row * 768 + v);
            x[i][0] = bf2f(u.x); x[i][1] = bf2f(u.y); x[i][2] = bf2f(u.z); x[i][3] = bf2f(u.w);
        }
#pragma unroll
        for (int e = 0; e < 4; e++) { s += x[i][e]; sq += x[i][e] * x[i][e]; }
    }
#pragma unroll
    for (int off = 1; off < 64; off <<= 1) {
        s  += __shfl_xor(s, off);
        sq += __shfl_xor(sq, off);
    }
    float mean = s * (1.f / 768.f);
    float var  = sq * (1.f / 768.f) - mean * mean;
    float rs   = rsqrtf(var + 1e-5f);
#pragma unroll
    for (int i = 0; i < 3; i++) {
        int v = i * 256 + lane * 4;
        float4 g = *(const float4*)(gam + v);
        float4 b = *(const float4*)(bet + v);
        ushort4 o;
        o.x = f2bf((x[i][0] - mean) * rs * g.x + b.x);
        o.y = f2bf((x[i][1] - mean) * rs * g.y + b.y);
        o.z = f2bf((x[i][2] - mean) * rs * g.z + b.z);
        o.w = f2bf((x[i][3] - mean) * rs * g.w + b.w);
        *(ushort4*)(dst + row * 768 + v) = o;
    }
}

// ---------------------------------------------------------------------------
// out[M][32] = A[M][768](bf16) @ W[32][768]^T + bias.  W resident in LDS.
// ---------------------------------------------------------------------------
__global__ __launch_bounds__(256) void proj32(
    const unsigned short* __restrict__ A, const float* __restrict__ W,
    const float* __restrict__ bias, unsigned short* __restrict__ out)
{
    __shared__ __align__(16) unsigned short lsW[32 * 776];
    __shared__ __align__(16) unsigned short lsA[128 * 40];
    const int t = threadIdx.x;

#pragma unroll
    for (int i = 0; i < 24; i++) {
        int fi = t + i * 256;
        int row = fi / 192;
        int c4  = fi % 192;
        float4 f = *(const float4*)(W + row * 768 + c4 * 4);
        ushort4 u;
        u.x = f2bf(f.x); u.y = f2bf(f.y); u.z = f2bf(f.z); u.w = f2bf(f.w);
        *(ushort4*)&lsW[row * 776 + c4 * 4] = u;
    }

    const size_t m0 = (size_t)blockIdx.x * 128;
    const int lane = t & 63, wave = t >> 6;
    const int wm = wave * 32;
    const int lr = lane & 15, kg = (lane >> 4) * 8;
    const int row_s = t >> 3, c4s = t & 7;

    f32x4 acc[2][2];
#pragma unroll
    for (int i = 0; i < 2; i++)
#pragma unroll
        for (int j = 0; j < 2; j++) acc[i][j] = (f32x4){0.f, 0.f, 0.f, 0.f};

    __syncthreads();

    for (int k0 = 0; k0 < 768; k0 += 32) {
#pragma unroll
        for (int i = 0; i < 4; i++) {
            int row = row_s + 32 * i;
            ushort4 v = *(const ushort4*)(A + (m0 + row) * 768 + k0 + c4s * 4);
            *(ushort4*)&lsA[row * 40 + c4s * 4] = v;
        }
        __syncthreads();
        short8 af[2], bw[2];
#pragma unroll
        for (int mi = 0; mi < 2; mi++)
            af[mi] = *(const short8*)&lsA[(wm + mi * 16 + lr) * 40 + kg];
#pragma unroll
        for (int ni = 0; ni < 2; ni++)
            bw[ni] = *(const short8*)&lsW[(ni * 16 + lr) * 776 + k0 + kg];
#pragma unroll
        for (int mi = 0; mi < 2; mi++)
#pragma unroll
            for (int ni = 0; ni < 2; ni++)
                acc[mi][ni] = __builtin_amdgcn_mfma_f32_16x16x32_bf16(
                    af[mi], bw[ni], acc[mi][ni], 0, 0, 0);
        __syncthreads();
    }

#pragma unroll
    for (int ni = 0; ni < 2; ni++) {
        int col = ni * 16 + lr;
        float bv = bias[col];
#pragma unroll
        for (int mi = 0; mi < 2; mi++) {
#pragma unroll
            for (int r = 0; r < 4; r++) {
                size_t grow = m0 + wm + mi * 16 + (lane >> 4) * 4 + r;
                out[grow * 32 + col] = f2bf(acc[mi][ni][r] + bv);
            }
        }
    }
}

// ---------------------------------------------------------------------------
// Attention: scores -> softmax(L=13) -> out_heads.  One wave per token.
// ---------------------------------------------------------------------------
__global__ __launch_bounds__(256) void attn_kernel(
    const unsigned short* __restrict__ qb, const unsigned short* __restrict__ kb,
    const unsigned short* __restrict__ kv, unsigned short* __restrict__ oh)
{
    __shared__ float lat[4][4][13];
    const int t = threadIdx.x, lane = t & 63, wave = t >> 6;
    const size_t m = (size_t)blockIdx.x * 4 + wave;

    if (lane < 32) {
        int j = lane;
        float qv = bf2f(qb[m * 32 + j]);
        float p[13];
#pragma unroll
        for (int l = 0; l < 13; l++)
            p[l] = qv * bf2f(kb[(m * 13 + l) * 32 + j]);
#pragma unroll
        for (int off = 1; off < 8; off <<= 1)
#pragma unroll
            for (int l = 0; l < 13; l++) p[l] += __shfl_xor(p[l], off);

        const float sc = 0.17677669529663687f; // 1 / (sqrt(8) * 2)
        float mx = -1e30f;
#pragma unroll
        for (int l = 0; l < 13; l++) { p[l] *= sc; mx = fmaxf(mx, p[l]); }
        float se = 0.f;
#pragma unroll
        for (int l = 0; l < 13; l++) { p[l] = __expf(p[l] - mx); se += p[l]; }
        float inv = 1.f / se;
        if ((j & 7) == 0) {
#pragma unroll
            for (int l = 0; l < 13; l++) lat[wave][j >> 3][l] = p[l] * inv;
        }
    }
    __syncthreads();

    float acc[4][3][4];
#pragma unroll
    for (int h = 0; h < 4; h++)
#pragma unroll
        for (int i = 0; i < 3; i++)
#pragma unroll
            for (int e = 0; e < 4; e++) acc[h][i][e] = 0.f;

    for (int l = 0; l < 13; l++) {
        float al[4];
#pragma unroll
        for (int h = 0; h < 4; h++) al[h] = lat[wave][h][l];
#pragma unroll
        for (int i = 0; i < 3; i++) {
            ushort4 u = *(const ushort4*)(kv + (m * 13 + l) * 768 + i * 256 + lane * 4);
            float xv[4] = {bf2f(u.x), bf2f(u.y), bf2f(u.z), bf2f(u.w)};
#pragma unroll
            for (int h = 0; h < 4; h++)
#pragma unroll
                for (int e = 0; e < 4; e++) acc[h][i][e] += al[h] * xv[e];
        }
    }
#pragma unroll
    for (int h = 0; h < 4; h++)
#pragma unroll
        for (int i = 0; i < 3; i++) {
            ushort4 o;
            o.x = f2bf(acc[h][i][0]); o.y = f2bf(acc[h][i][1]);
            o.z = f2bf(acc[h][i][2]); o.w = f2bf(acc[h][i][3]);
            *(ushort4*)(oh + m * 3072 + h * 768 + i * 256 + lane * 4) = o;
        }
}

// ---------------------------------------------------------------------------
extern "C" void kernel_launch(void* const* d_in, const int* in_sizes, int n_in,
                              void* d_out, int out_size, void* d_ws, size_t ws_size,
                              hipStream_t stream) {
    const float* base  = (const float*)d_in[0];   // (B,T,D)
    const float* reps  = (const float*)d_in[1];   // (L,B,T,R)
    const float* aw    = (const float*)d_in[2];   // (L,V,R)
    const float* ab    = (const float*)d_in[3];   // (L,V)
    const float* qg    = (const float*)d_in[4];
    const float* qbeta = (const float*)d_in[5];
    const float* kvg   = (const float*)d_in[6];
    const float* kvb   = (const float*)d_in[7];
    const float* qw    = (const float*)d_in[8];   // (32,768)
    const float* qbias = (const float*)d_in[9];
    const float* kw    = (const float*)d_in[10];  // (32,768)
    const float* kbias = (const float*)d_in[11];
    const float* ow    = (const float*)d_in[12];  // (768,3072)
    const float* obias = (const float*)d_in[13];
    float* out = (float*)d_out;

    // ws layout (ushort units).  Total 230,686,720 bytes (< 233.8 MB proven).
    unsigned short* aligned = (unsigned short*)d_ws;                  // [MROWS][768]
    unsigned short* U    = aligned + (size_t)MROWS * 768;             // 50.3 MB union:
                                                                      //   reps group (<=4 layers bf16)
                                                                      //   -> Qn [8192][768]
                                                                      //   -> oh [8192][3072]
    unsigned short* kbuf = U + (size_t)4 * MTOK * 768;                // [MROWS][32]
    unsigned short* qbuf = kbuf + (size_t)MROWS * 32;                 // [8192][32]
    unsigned short* awg  = qbuf + (size_t)MTOK * 32;                  // 4x[768][768]
    unsigned short* owb  = awg + (size_t)4 * 768 * 768;               // [768][3072]

    // 0. convert out_w once
    {
        long n = (long)768 * 3072;
        int g = (int)((n / 8 + 255) / 256); if (g > 4096) g = 4096;
        conv_f32_bf16<<<g, 256, 0, stream>>>(ow, owb, n);
    }

    // 1. aligner GEMM in groups of 4 layers: convert -> m97 GEMM
    for (int grp = 0; grp < 4; grp++) {
        int l0 = grp * 4;
        int gl = (l0 + 4 <= NL) ? 4 : (NL - l0);
        if (gl <= 0) break;
        long nr = (long)gl * MTOK * 768;
        int g1 = (int)((nr / 8 + 255) / 256); if (g1 > 4096) g1 = 4096;
        conv_f32_bf16<<<g1, 256, 0, stream>>>(reps + (size_t)l0 * MTOK * 768, U, nr);
        long nw = (long)gl * 768 * 768;
        int g2 = (int)((nw / 8 + 255) / 256); if (g2 > 4096) g2 = 4096;
        conv_f32_bf16<<<g2, 256, 0, stream>>>(aw + (size_t)l0 * 768 * 768, awg, nw);

        dim3 gg(NV / 128, MTOK / 128, gl);
        gemm_bf16_nt<false><<<gg, 256, 0, stream>>>(
            U, awg, ab + (size_t)l0 * 768, aligned + (size_t)l0 * 768,
            768, (long)MTOK * 768, (long)768 * 768, 768,
            768L, (long)NL * 768);
    }

    // 2. LayerNorms
    ln_rows<false><<<MROWS / 4, 256, 0, stream>>>(aligned, aligned, kvg, kvb);
    unsigned short* Qn = U;   // reps group buffer now dead
    ln_rows<true><<<MTOK / 4, 256, 0, stream>>>(base, Qn, qg, qbeta);

    // 3. k/q projections
    proj32<<<MROWS / 128, 256, 0, stream>>>(aligned, kw, kbias, kbuf);
    proj32<<<MTOK / 128, 256, 0, stream>>>(Qn, qw, qbias, qbuf);

    // 4. attention -> out_heads (overwrites U; Qn dead)
    unsigned short* oh = U;
    attn_kernel<<<MTOK / 4, 256, 0, stream>>>(qbuf, kbuf, aligned, oh);

    // 5. out = out_heads @ out_w^T + out_b  (fp32 out)
    dim3 g2(ND / 128, MTOK / 128, 1);
    gemm_bf16_nt<true><<<g2, 256, 0, stream>>>(
        oh, owb, obias, out,
        3072, 0L, 0L, 0, 0L, 768L);
}

// Round 3
// 559.398 us; speedup vs baseline: 1.1228x; 1.0328x over previous
//
#include <hip/hip_runtime.h>
#include <stdint.h>

#define NB 8
#define NT 1024
#define ND 768
#define NV 768
#define NL 13
#define MTOK (NB*NT)          // 8192
#define MROWS (MTOK*NL)       // 106496

typedef __attribute__((ext_vector_type(8))) short short8;
typedef __attribute__((ext_vector_type(4))) float f32x4;

__device__ __forceinline__ unsigned short f2bf(float f) {
    union { float f; unsigned u; } v; v.f = f;
    unsigned r = v.u + 0x7FFFu + ((v.u >> 16) & 1u);
    return (unsigned short)(r >> 16);
}
__device__ __forceinline__ float bf2f(unsigned short u) {
    union { unsigned u; float f; } v; v.u = ((unsigned)u) << 16;
    return v.f;
}
__device__ __forceinline__ unsigned cvtpk(float lo, float hi) {
    unsigned r;
    asm("v_cvt_pk_bf16_f32 %0, %1, %2" : "=v"(r) : "v"(lo), "v"(hi));
    return r;
}
__device__ __forceinline__ void gload16(const void* g, void* l) {
    __builtin_amdgcn_global_load_lds(
        (const __attribute__((address_space(1))) unsigned int*)g,
        (__attribute__((address_space(3))) unsigned int*)l, 16, 0, 0);
}

// ---------------------------------------------------------------------------
// fp32 -> bf16 bulk convert (weights only now)
// ---------------------------------------------------------------------------
__global__ __launch_bounds__(256) void conv_f32_bf16(
    const float* __restrict__ s, unsigned short* __restrict__ d, long n)
{
    long i = ((long)blockIdx.x * 256 + threadIdx.x) * 8;
    long st = (long)gridDim.x * 2048;
    for (; i < n; i += st) {
        float4 a = *(const float4*)(s + i);
        float4 b = *(const float4*)(s + i + 4);
        ushort4 u0, u1;
        u0.x = f2bf(a.x); u0.y = f2bf(a.y); u0.z = f2bf(a.z); u0.w = f2bf(a.w);
        u1.x = f2bf(b.x); u1.y = f2bf(b.y); u1.z = f2bf(b.z); u1.w = f2bf(b.w);
        *(ushort4*)(d + i)     = u0;
        *(ushort4*)(d + i + 4) = u1;
    }
}

// ---------------------------------------------------------------------------
// GEMM1: C(bf16) = A(fp32) * B(bf16)^T + bias.  A staged fp32 via
// global_load_lds with source-chunk XOR swizzle; in-register cvt_pk to bf16.
// 128x128 tile, BK=32, double-buffered.  grid = (N/128, M/128, L).
// ---------------------------------------------------------------------------
__global__ __launch_bounds__(256) void gemm_f32a(
    const float* __restrict__ A, const unsigned short* __restrict__ B,
    const float* __restrict__ biasBase, unsigned short* __restrict__ C,
    int K, long aLS, long bLS, int biasLS, long cLayerOff, long cRowStride)
{
    __shared__ __align__(16) float          lsA[2][128 * 32];
    __shared__ __align__(16) unsigned short lsB[2][128 * 32];

    const int l = blockIdx.z;
    const long m0 = (long)blockIdx.y * 128;
    const long n0 = (long)blockIdx.x * 128;
    const int t = threadIdx.x, lane = t & 63, wave = t >> 6;

    const float* Ab = A + (size_t)l * aLS;
    const unsigned short* Bb = B + (size_t)l * bLS;
    const float* bias = biasBase + (size_t)l * biasLS;

    // A staging: dest linear [128 rows][8 chunks of 16B]; source chunk swizzled
    const int arow = wave * 8 + (lane >> 3);        // row within 32-row slab
    const int achk = (lane & 7) ^ (lane >> 3);      // swizzled source chunk
    const int dA   = wave * 1024 + lane * 16;       // dest byte within 4KB slab
    // B staging: linear [128 rows][64B]
    const int brow = wave * 16 + (lane >> 2);
    const int bcol = (lane & 3) * 16;
    const int dB   = wave * 1024 + lane * 16;

    const int wm = (wave >> 1) * 64;
    const int wn = (wave & 1) * 64;
    const int lr = lane & 15;
    const int g  = lane >> 4;
    const int kg = g * 8;

    f32x4 acc[4][4];
#pragma unroll
    for (int i = 0; i < 4; i++)
#pragma unroll
        for (int j = 0; j < 4; j++) acc[i][j] = (f32x4){0.f, 0.f, 0.f, 0.f};

    auto STAGE = [&](int buf, int k0) {
        char* la = (char*)lsA[buf];
        char* lb = (char*)lsB[buf];
#pragma unroll
        for (int i = 0; i < 4; i++) {
            const char* src = (const char*)(Ab + (m0 + i * 32 + arow) * (size_t)K + k0) + achk * 16;
            gload16(src, la + i * 4096 + dA);
        }
#pragma unroll
        for (int i = 0; i < 2; i++) {
            const char* src = (const char*)(Bb + (n0 + i * 64 + brow) * (size_t)K + k0) + bcol;
            gload16(src, lb + i * 4096 + dB);
        }
    };
    auto COMP = [&](int buf) {
        short8 af[4], bv[4];
        const float* pa = lsA[buf];
        const unsigned short* pb = lsB[buf];
#pragma unroll
        for (int mi = 0; mi < 4; mi++) {
            int row = wm + mi * 16 + lr;
            const char* base = (const char*)pa + row * 128;
            float4 x0 = *(const float4*)(base + (((2 * g + 0) ^ (row & 7)) << 4));
            float4 x1 = *(const float4*)(base + (((2 * g + 1) ^ (row & 7)) << 4));
            union { short8 s; unsigned u[4]; } ua;
            ua.u[0] = cvtpk(x0.x, x0.y); ua.u[1] = cvtpk(x0.z, x0.w);
            ua.u[2] = cvtpk(x1.x, x1.y); ua.u[3] = cvtpk(x1.z, x1.w);
            af[mi] = ua.s;
        }
#pragma unroll
        for (int ni = 0; ni < 4; ni++)
            bv[ni] = *(const short8*)&pb[(wn + ni * 16 + lr) * 32 + kg];
#pragma unroll
        for (int mi = 0; mi < 4; mi++)
#pragma unroll
            for (int ni = 0; ni < 4; ni++)
                acc[mi][ni] = __builtin_amdgcn_mfma_f32_16x16x32_bf16(
                    af[mi], bv[ni], acc[mi][ni], 0, 0, 0);
    };

    STAGE(0, 0);
    __syncthreads();
    int cur = 0;
    const int nst = K >> 5;
    for (int ks = 1; ks < nst; ks++) {
        STAGE(cur ^ 1, ks * 32);
        COMP(cur);
        __syncthreads();
        cur ^= 1;
    }
    COMP(cur);

#pragma unroll
    for (int ni = 0; ni < 4; ni++) {
        long col = n0 + wn + ni * 16 + lr;
        float bvs = bias[col];
#pragma unroll
        for (int mi = 0; mi < 4; mi++) {
#pragma unroll
            for (int r = 0; r < 4; r++) {
                long grow = m0 + wm + mi * 16 + (lane >> 4) * 4 + r;
                size_t coff = (size_t)grow * cRowStride + (size_t)l * cLayerOff + col;
                C[coff] = f2bf(acc[mi][ni][r] + bvs);
            }
        }
    }
}

// ---------------------------------------------------------------------------
// GEMM2 (unchanged m97): C = A(bf16) * B(bf16)^T + bias, fp32 out.
// ---------------------------------------------------------------------------
__global__ __launch_bounds__(256) void gemm_bf16_nt(
    const unsigned short* __restrict__ A, const unsigned short* __restrict__ B,
    const float* __restrict__ bias, float* __restrict__ C,
    int K, long cRowStride)
{
    __shared__ __align__(16) unsigned short lsA[2][128 * 32];
    __shared__ __align__(16) unsigned short lsB[2][128 * 32];

    const long m0 = (long)blockIdx.y * 128;
    const long n0 = (long)blockIdx.x * 128;
    const int t = threadIdx.x, lane = t & 63, wave = t >> 6;

    const int d0 = wave * 1024 + lane * 16;
    const int r0 = d0 >> 6, cb = d0 & 63;
    const int r1 = r0 + 64;
    const char* aS0 = (const char*)(A + (m0 + r0) * (size_t)K) + cb;
    const char* aS1 = (const char*)(A + (m0 + r1) * (size_t)K) + cb;
    const char* bS0 = (const char*)(B + (n0 + r0) * (size_t)K) + cb;
    const char* bS1 = (const char*)(B + (n0 + r1) * (size_t)K) + cb;

    const int wm = (wave >> 1) * 64;
    const int wn = (wave & 1) * 64;
    const int lr = lane & 15;
    const int kg = (lane >> 4) * 8;

    f32x4 acc[4][4];
#pragma unroll
    for (int i = 0; i < 4; i++)
#pragma unroll
        for (int j = 0; j < 4; j++) acc[i][j] = (f32x4){0.f, 0.f, 0.f, 0.f};

    auto STAGE = [&](int buf, int k0) {
        long kb = (long)k0 * 2;
        char* la = (char*)lsA[buf];
        char* lb = (char*)lsB[buf];
        gload16(aS0 + kb, la + d0);
        gload16(aS1 + kb, la + d0 + 4096);
        gload16(bS0 + kb, lb + d0);
        gload16(bS1 + kb, lb + d0 + 4096);
    };
    auto COMP = [&](int buf) {
        short8 af[4], bv[4];
        const unsigned short* pa = lsA[buf];
        const unsigned short* pb = lsB[buf];
#pragma unroll
        for (int mi = 0; mi < 4; mi++)
            af[mi] = *(const short8*)&pa[(wm + mi * 16 + lr) * 32 + kg];
#pragma unroll
        for (int ni = 0; ni < 4; ni++)
            bv[ni] = *(const short8*)&pb[(wn + ni * 16 + lr) * 32 + kg];
#pragma unroll
        for (int mi = 0; mi < 4; mi++)
#pragma unroll
            for (int ni = 0; ni < 4; ni++)
                acc[mi][ni] = __builtin_amdgcn_mfma_f32_16x16x32_bf16(
                    af[mi], bv[ni], acc[mi][ni], 0, 0, 0);
    };

    STAGE(0, 0);
    __syncthreads();
    int cur = 0;
    const int nst = K >> 5;
    for (int ks = 1; ks < nst; ks++) {
        STAGE(cur ^ 1, ks * 32);
        COMP(cur);
        __syncthreads();
        cur ^= 1;
    }
    COMP(cur);

#pragma unroll
    for (int ni = 0; ni < 4; ni++) {
        long col = n0 + wn + ni * 16 + lr;
        float bvs = bias[col];
#pragma unroll
        for (int mi = 0; mi < 4; mi++) {
#pragma unroll
            for (int r = 0; r < 4; r++) {
                long grow = m0 + wm + mi * 16 + (lane >> 4) * 4 + r;
                C[(size_t)grow * cRowStride + col] = acc[mi][ni][r] + bvs;
            }
        }
    }
}

// ---------------------------------------------------------------------------
// Row stats: mean, rsqrt(var+eps) per 768-wide bf16 row.  One wave per row.
// ---------------------------------------------------------------------------
__global__ __launch_bounds__(256) void stats_rows(
    const unsigned short* __restrict__ src, float2* __restrict__ st)
{
    const int lane = threadIdx.x & 63;
    const int wave = threadIdx.x >> 6;
    const size_t row = (size_t)blockIdx.x * 4 + wave;

    float s = 0.f, sq = 0.f;
#pragma unroll
    for (int i = 0; i < 3; i++) {
        int v = i * 256 + lane * 4;
        ushort4 u = *(const ushort4*)(src + row * 768 + v);
        float x0 = bf2f(u.x), x1 = bf2f(u.y), x2 = bf2f(u.z), x3 = bf2f(u.w);
        s += x0 + x1 + x2 + x3;
        sq += x0 * x0 + x1 * x1 + x2 * x2 + x3 * x3;
    }
#pragma unroll
    for (int off = 1; off < 64; off <<= 1) {
        s  += __shfl_xor(s, off);
        sq += __shfl_xor(sq, off);
    }
    if (lane == 0) {
        float mean = s * (1.f / 768.f);
        float var  = sq * (1.f / 768.f) - mean * mean;
        st[row] = make_float2(mean, rsqrtf(var + 1e-5f));
    }
}

// ---------------------------------------------------------------------------
// Fold kvln gamma into k_w; compute s_k = sum(kw*g), c_k = kw.b + k_bias.
// grid = 32 blocks (one per output q), 256 threads.
// ---------------------------------------------------------------------------
__global__ __launch_bounds__(256) void wtrans(
    const float* __restrict__ kw, const float* __restrict__ kvg,
    const float* __restrict__ kvb, const float* __restrict__ kbias,
    float* __restrict__ kwp, float* __restrict__ skv, float* __restrict__ ckv)
{
    __shared__ float red[8];
    const int q = blockIdx.x, t = threadIdx.x;
    const int lane = t & 63, wave = t >> 6;
    float s = 0.f, c = 0.f;
    for (int v = t; v < 768; v += 256) {
        float w = kw[q * 768 + v];
        float wp = w * kvg[v];
        kwp[q * 768 + v] = wp;
        s += wp;
        c += w * kvb[v];
    }
#pragma unroll
    for (int off = 1; off < 64; off <<= 1) {
        s += __shfl_xor(s, off);
        c += __shfl_xor(c, off);
    }
    if (lane == 0) { red[wave] = s; red[4 + wave] = c; }
    __syncthreads();
    if (t == 0) {
        skv[q] = red[0] + red[1] + red[2] + red[3];
        ckv[q] = red[4] + red[5] + red[6] + red[7] + kbias[q];
    }
}

// ---------------------------------------------------------------------------
// LayerNorm rows of 768 (fp32 src) -> bf16.  Used for Q side only.
// ---------------------------------------------------------------------------
__global__ __launch_bounds__(256) void ln_rows_f32(
    const float* __restrict__ src, unsigned short* __restrict__ dst,
    const float* __restrict__ gam, const float* __restrict__ bet)
{
    const int lane = threadIdx.x & 63;
    const int wave = threadIdx.x >> 6;
    const size_t row = (size_t)blockIdx.x * 4 + wave;

    float x[3][4];
    float s = 0.f, sq = 0.f;
#pragma unroll
    for (int i = 0; i < 3; i++) {
        int v = i * 256 + lane * 4;
        float4 f = *(const float4*)(src + row * 768 + v);
        x[i][0] = f.x; x[i][1] = f.y; x[i][2] = f.z; x[i][3] = f.w;
#pragma unroll
        for (int e = 0; e < 4; e++) { s += x[i][e]; sq += x[i][e] * x[i][e]; }
    }
#pragma unroll
    for (int off = 1; off < 64; off <<= 1) {
        s  += __shfl_xor(s, off);
        sq += __shfl_xor(sq, off);
    }
    float mean = s * (1.f / 768.f);
    float var  = sq * (1.f / 768.f) - mean * mean;
    float rs   = rsqrtf(var + 1e-5f);
#pragma unroll
    for (int i = 0; i < 3; i++) {
        int v = i * 256 + lane * 4;
        float4 gg = *(const float4*)(gam + v);
        float4 bb = *(const float4*)(bet + v);
        ushort4 o;
        o.x = f2bf((x[i][0] - mean) * rs * gg.x + bb.x);
        o.y = f2bf((x[i][1] - mean) * rs * gg.y + bb.y);
        o.z = f2bf((x[i][2] - mean) * rs * gg.z + bb.z);
        o.w = f2bf((x[i][3] - mean) * rs * gg.w + bb.w);
        *(ushort4*)(dst + row * 768 + v) = o;
    }
}

// ---------------------------------------------------------------------------
// proj32: out[M][32] = A[M][768](bf16) @ W[32][768](f32)^T + bias (plain).
// ---------------------------------------------------------------------------
__global__ __launch_bounds__(256) void proj32(
    const unsigned short* __restrict__ A, const float* __restrict__ W,
    const float* __restrict__ bias, unsigned short* __restrict__ out)
{
    __shared__ __align__(16) unsigned short lsW[32 * 776];
    __shared__ __align__(16) unsigned short lsA[128 * 40];
    const int t = threadIdx.x;

#pragma unroll
    for (int i = 0; i < 24; i++) {
        int fi = t + i * 256;
        int row = fi / 192;
        int c4  = fi % 192;
        float4 f = *(const float4*)(W + row * 768 + c4 * 4);
        ushort4 u;
        u.x = f2bf(f.x); u.y = f2bf(f.y); u.z = f2bf(f.z); u.w = f2bf(f.w);
        *(ushort4*)&lsW[row * 776 + c4 * 4] = u;
    }

    const size_t m0 = (size_t)blockIdx.x * 128;
    const int lane = t & 63, wave = t >> 6;
    const int wm = wave * 32;
    const int lr = lane & 15, kg = (lane >> 4) * 8;
    const int row_s = t >> 3, c4s = t & 7;

    f32x4 acc[2][2];
#pragma unroll
    for (int i = 0; i < 2; i++)
#pragma unroll
        for (int j = 0; j < 2; j++) acc[i][j] = (f32x4){0.f, 0.f, 0.f, 0.f};

    __syncthreads();

    for (int k0 = 0; k0 < 768; k0 += 32) {
#pragma unroll
        for (int i = 0; i < 4; i++) {
            int row = row_s + 32 * i;
            ushort4 v = *(const ushort4*)(A + (m0 + row) * 768 + k0 + c4s * 4);
            *(ushort4*)&lsA[row * 40 + c4s * 4] = v;
        }
        __syncthreads();
        short8 af[2], bw[2];
#pragma unroll
        for (int mi = 0; mi < 2; mi++)
            af[mi] = *(const short8*)&lsA[(wm + mi * 16 + lr) * 40 + kg];
#pragma unroll
        for (int ni = 0; ni < 2; ni++)
            bw[ni] = *(const short8*)&lsW[(ni * 16 + lr) * 776 + k0 + kg];
#pragma unroll
        for (int mi = 0; mi < 2; mi++)
#pragma unroll
            for (int ni = 0; ni < 2; ni++)
                acc[mi][ni] = __builtin_amdgcn_mfma_f32_16x16x32_bf16(
                    af[mi], bw[ni], acc[mi][ni], 0, 0, 0);
        __syncthreads();
    }

#pragma unroll
    for (int ni = 0; ni < 2; ni++) {
        int col = ni * 16 + lr;
        float bv = bias[col];
#pragma unroll
        for (int mi = 0; mi < 2; mi++) {
#pragma unroll
            for (int r = 0; r < 4; r++) {
                size_t grow = m0 + wm + mi * 16 + (lane >> 4) * 4 + r;
                out[grow * 32 + col] = f2bf(acc[mi][ni][r] + bv);
            }
        }
    }
}

// ---------------------------------------------------------------------------
// proj32k: k = rs*(dot(x_raw, kwp) - mean*s_k) + c_k  (LN folded out).
// ---------------------------------------------------------------------------
__global__ __launch_bounds__(256) void proj32k(
    const unsigned short* __restrict__ A, const float* __restrict__ W,
    const float2* __restrict__ st, const float* __restrict__ skv,
    const float* __restrict__ ckv, unsigned short* __restrict__ out)
{
    __shared__ __align__(16) unsigned short lsW[32 * 776];
    __shared__ __align__(16) unsigned short lsA[128 * 40];
    const int t = threadIdx.x;

#pragma unroll
    for (int i = 0; i < 24; i++) {
        int fi = t + i * 256;
        int row = fi / 192;
        int c4  = fi % 192;
        float4 f = *(const float4*)(W + row * 768 + c4 * 4);
        ushort4 u;
        u.x = f2bf(f.x); u.y = f2bf(f.y); u.z = f2bf(f.z); u.w = f2bf(f.w);
        *(ushort4*)&lsW[row * 776 + c4 * 4] = u;
    }

    const size_t m0 = (size_t)blockIdx.x * 128;
    const int lane = t & 63, wave = t >> 6;
    const int wm = wave * 32;
    const int lr = lane & 15, kg = (lane >> 4) * 8;
    const int row_s = t >> 3, c4s = t & 7;

    f32x4 acc[2][2];
#pragma unroll
    for (int i = 0; i < 2; i++)
#pragma unroll
        for (int j = 0; j < 2; j++) acc[i][j] = (f32x4){0.f, 0.f, 0.f, 0.f};

    __syncthreads();

    for (int k0 = 0; k0 < 768; k0 += 32) {
#pragma unroll
        for (int i = 0; i < 4; i++) {
            int row = row_s + 32 * i;
            ushort4 v = *(const ushort4*)(A + (m0 + row) * 768 + k0 + c4s * 4);
            *(ushort4*)&lsA[row * 40 + c4s * 4] = v;
        }
        __syncthreads();
        short8 af[2], bw[2];
#pragma unroll
        for (int mi = 0; mi < 2; mi++)
            af[mi] = *(const short8*)&lsA[(wm + mi * 16 + lr) * 40 + kg];
#pragma unroll
        for (int ni = 0; ni < 2; ni++)
            bw[ni] = *(const short8*)&lsW[(ni * 16 + lr) * 776 + k0 + kg];
#pragma unroll
        for (int mi = 0; mi < 2; mi++)
#pragma unroll
            for (int ni = 0; ni < 2; ni++)
                acc[mi][ni] = __builtin_amdgcn_mfma_f32_16x16x32_bf16(
                    af[mi], bw[ni], acc[mi][ni], 0, 0, 0);
        __syncthreads();
    }

#pragma unroll
    for (int ni = 0; ni < 2; ni++) {
        int col = ni * 16 + lr;
        float sk = skv[col], ck = ckv[col];
#pragma unroll
        for (int mi = 0; mi < 2; mi++) {
#pragma unroll
            for (int r = 0; r < 4; r++) {
                size_t grow = m0 + wm + mi * 16 + (lane >> 4) * 4 + r;
                float2 s_ = st[grow];
                out[grow * 32 + col] = f2bf(s_.y * (acc[mi][ni][r] - s_.x * sk) + ck);
            }
        }
    }
}

// ---------------------------------------------------------------------------
// Attention on RAW aligned values with LN folded in:
// oh[h,v] = g[v]*(sum_l (a[l]*rs_l) x[l,v] - corr_h) + b[v],
// corr_h = sum_l a[l]*rs_l*mean_l.  One wave per token.
// ---------------------------------------------------------------------------
__global__ __launch_bounds__(256) void attn2(
    const unsigned short* __restrict__ qb, const unsigned short* __restrict__ kb,
    const unsigned short* __restrict__ kv, const float2* __restrict__ st,
    const float* __restrict__ gv, const float* __restrict__ bvv,
    unsigned short* __restrict__ oh)
{
    __shared__ float lat[4][4][13];
    __shared__ float latc[4][4];
    const int t = threadIdx.x, lane = t & 63, wave = t >> 6;
    const size_t m = (size_t)blockIdx.x * 4 + wave;

    if (lane < 32) {
        int j = lane;
        float qv = bf2f(qb[m * 32 + j]);
        float p[13];
#pragma unroll
        for (int l = 0; l < 13; l++)
            p[l] = qv * bf2f(kb[(m * 13 + l) * 32 + j]);
#pragma unroll
        for (int off = 1; off < 8; off <<= 1)
#pragma unroll
            for (int l = 0; l < 13; l++) p[l] += __shfl_xor(p[l], off);

        const float sc = 0.17677669529663687f; // 1 / (sqrt(8) * 2)
        float mx = -1e30f;
#pragma unroll
        for (int l = 0; l < 13; l++) { p[l] *= sc; mx = fmaxf(mx, p[l]); }
        float se = 0.f;
#pragma unroll
        for (int l = 0; l < 13; l++) { p[l] = __expf(p[l] - mx); se += p[l]; }
        float inv = 1.f / se;
        if ((j & 7) == 0) {
            int h = j >> 3;
            float corr = 0.f;
#pragma unroll
            for (int l = 0; l < 13; l++) {
                float2 s_ = st[m * 13 + l];
                float wl = p[l] * inv * s_.y;
                lat[wave][h][l] = wl;
                corr += wl * s_.x;
            }
            latc[wave][h] = corr;
        }
    }
    __syncthreads();

    f32x4 g4[3], b4[3];
#pragma unroll
    for (int i = 0; i < 3; i++) {
        g4[i] = *(const f32x4*)(gv + i * 256 + lane * 4);
        b4[i] = *(const f32x4*)(bvv + i * 256 + lane * 4);
    }

    float acc[4][3][4];
#pragma unroll
    for (int h = 0; h < 4; h++)
#pragma unroll
        for (int i = 0; i < 3; i++)
#pragma unroll
            for (int e = 0; e < 4; e++) acc[h][i][e] = 0.f;

    for (int l = 0; l < 13; l++) {
        float al[4];
#pragma unroll
        for (int h = 0; h < 4; h++) al[h] = lat[wave][h][l];
#pragma unroll
        for (int i = 0; i < 3; i++) {
            ushort4 u = *(const ushort4*)(kv + (m * 13 + l) * 768 + i * 256 + lane * 4);
            float xv[4] = {bf2f(u.x), bf2f(u.y), bf2f(u.z), bf2f(u.w)};
#pragma unroll
            for (int h = 0; h < 4; h++)
#pragma unroll
                for (int e = 0; e < 4; e++) acc[h][i][e] += al[h] * xv[e];
        }
    }
#pragma unroll
    for (int h = 0; h < 4; h++) {
        float ch = latc[wave][h];
#pragma unroll
        for (int i = 0; i < 3; i++) {
            ushort4 o;
            o.x = f2bf(g4[i][0] * (acc[h][i][0] - ch) + b4[i][0]);
            o.y = f2bf(g4[i][1] * (acc[h][i][1] - ch) + b4[i][1]);
            o.z = f2bf(g4[i][2] * (acc[h][i][2] - ch) + b4[i][2]);
            o.w = f2bf(g4[i][3] * (acc[h][i][3] - ch) + b4[i][3]);
            *(ushort4*)(oh + m * 3072 + h * 768 + i * 256 + lane * 4) = o;
        }
    }
}

// ---------------------------------------------------------------------------
extern "C" void kernel_launch(void* const* d_in, const int* in_sizes, int n_in,
                              void* d_out, int out_size, void* d_ws, size_t ws_size,
                              hipStream_t stream) {
    const float* base  = (const float*)d_in[0];   // (B,T,D)
    const float* reps  = (const float*)d_in[1];   // (L,B,T,R)
    const float* aw    = (const float*)d_in[2];   // (L,V,R)
    const float* ab    = (const float*)d_in[3];   // (L,V)
    const float* qg    = (const float*)d_in[4];
    const float* qbeta = (const float*)d_in[5];
    const float* kvg   = (const float*)d_in[6];
    const float* kvb   = (const float*)d_in[7];
    const float* qw    = (const float*)d_in[8];   // (32,768)
    const float* qbias = (const float*)d_in[9];
    const float* kw    = (const float*)d_in[10];  // (32,768)
    const float* kbias = (const float*)d_in[11];
    const float* ow    = (const float*)d_in[12];  // (768,3072)
    const float* obias = (const float*)d_in[13];
    float* out = (float*)d_out;

    // ws layout — total ~226.9 MB
    float2* stats = (float2*)d_ws;                              // [MROWS]
    float* kwp = (float*)(stats + MROWS);                       // [32][768]
    float* skv = kwp + 32 * 768;                                // [32]
    float* ckv = skv + 32;                                      // [32]
    unsigned short* aligned = (unsigned short*)(ckv + 32);      // [MROWS][768]
    unsigned short* UNION = aligned + (size_t)MROWS * 768;      // 25.2M ushorts:
                                                                //  awb -> Qn -> oh
    unsigned short* kbuf = UNION + (size_t)MTOK * 3072;         // [MROWS][32]
    unsigned short* qbuf = kbuf + (size_t)MROWS * 32;           // [MTOK][32]
    unsigned short* owb  = qbuf + (size_t)MTOK * 32;            // [768][3072]

    unsigned short* awb = UNION;   // 13*768*768 = 7.67M ushorts (fits in UNION)

    // 0. weight conversions + LN folding precompute
    {
        long n = (long)NL * 768 * 768;
        conv_f32_bf16<<<(int)(n / 8 / 256), 256, 0, stream>>>(aw, awb, n);
        long n2 = (long)768 * 3072;
        conv_f32_bf16<<<(int)(n2 / 8 / 256), 256, 0, stream>>>(ow, owb, n2);
        wtrans<<<32, 256, 0, stream>>>(kw, kvg, kvb, kbias, kwp, skv, ckv);
    }

    // 1. aligner GEMM: fp32 A staged directly, converted in-register
    dim3 g1(NV / 128, MTOK / 128, NL);
    gemm_f32a<<<g1, 256, 0, stream>>>(
        reps, awb, ab, aligned,
        768, (long)MTOK * 768, (long)768 * 768, 768,
        768L, (long)NL * 768);

    // 2. per-row stats of raw aligned (for folded LN)
    stats_rows<<<MROWS / 4, 256, 0, stream>>>(aligned, stats);

    // 3. q side: LN(base) -> Qn, then proj32 (awb dead, reuse UNION)
    unsigned short* Qn = UNION;
    ln_rows_f32<<<MTOK / 4, 256, 0, stream>>>(base, Qn, qg, qbeta);
    proj32<<<MTOK / 128, 256, 0, stream>>>(Qn, qw, qbias, qbuf);

    // 4. k projection on raw aligned with LN-folded fixup
    proj32k<<<MROWS / 128, 256, 0, stream>>>(aligned, kwp, stats, skv, ckv, kbuf);

    // 5. attention on raw aligned (Qn dead, reuse UNION for oh)
    unsigned short* oh = UNION;
    attn2<<<MTOK / 4, 256, 0, stream>>>(qbuf, kbuf, aligned, stats, kvg, kvb, oh);

    // 6. out = out_heads @ out_w^T + out_b (fp32)
    dim3 g2(ND / 128, MTOK / 128, 1);
    gemm_bf16_nt<<<g2, 256, 0, stream>>>(oh, owb, obias, out, 3072, 768L);
}